// Round 10
// baseline (273.297 us; speedup 1.0000x reference)
//
#include <hip/hip_runtime.h>
#include <stdint.h>
#include <math.h>

#define NN 2048
#define BB 8
#define BN (BB*NN)
#define KK 16
#define EE (BN*KK)
#define HID 128
#define PROJ_D 256
#define QPB 16   // queries (waves) per knn block

typedef unsigned long long u64;
typedef unsigned short ushort_t;
typedef __attribute__((ext_vector_type(8))) short short8;
typedef __attribute__((ext_vector_type(4))) float f32x4;

__device__ __forceinline__ u64 wave_min_u64(u64 v) {
  #pragma unroll
  for (int off = 32; off > 0; off >>= 1) {
    u64 o = __shfl_xor(v, off);
    v = o < v ? o : v;
  }
  return v;
}

// ---------------- kNN + fused degree count (round-5/6 design, unchanged) ----
__global__ __launch_bounds__(1024) void knn_kernel(const float* __restrict__ pos,
                                                   int* __restrict__ nbr,
                                                   int* __restrict__ cnt) {
  __shared__ float4 Ps[NN];
  __shared__ unsigned Hist[QPB * 256];
  const int b  = blockIdx.x >> 7;
  const int qb = blockIdx.x & 127;
  const int wave = threadIdx.x >> 6;
  const int lane = threadIdx.x & 63;
  const int i = qb * QPB + wave;
  const float* P = pos + (size_t)b * NN * 3;

  for (int t = threadIdx.x; t < NN; t += 1024)
    Ps[t] = make_float4(P[t*3], P[t*3+1], P[t*3+2], 0.f);
  __syncthreads();

  const float4 pi = Ps[i];
  const float xi = pi.x, yi = pi.y, zi = pi.z;
  unsigned* H = &Hist[wave * 256];

  float d[32];
  #pragma unroll
  for (int t = 0; t < 32; t++) {
    int j = t * 64 + lane;
    float4 pj = Ps[j];
    float ax = fabsf(xi - pj.x), ay = fabsf(yi - pj.y), az = fabsf(zi - pj.z);
    float dx = fminf(ax, 1.0f - ax);
    float dy = fminf(ay, 1.0f - ay);
    float dz = fminf(az, 1.0f - az);
    float s = __fadd_rn(__fadd_rn(__fadd_rn(__fmul_rn(dx,dx), __fmul_rn(dy,dy)),
                                  __fmul_rn(dz,dz)), 1e-12f);
    d[t] = __fsqrt_rn(s);
  }

  float scale = 1024.0f;
  int bstar = 0; unsigned C = 0;
  for (;;) {
    *(uint4*)&H[lane * 4] = make_uint4(0u, 0u, 0u, 0u);
    #pragma unroll
    for (int t = 0; t < 32; t++) {
      int bin = (int)(d[t] * scale);
      if (bin < 256) atomicAdd(&H[bin], 1u);
    }
    uint4 cv = *(const uint4*)&H[lane * 4];
    unsigned s4 = cv.x + cv.y + cv.z + cv.w;
    unsigned incl = s4;
    #pragma unroll
    for (int off = 1; off < 64; off <<= 1) {
      unsigned v = __shfl_up(incl, off);
      if (lane >= off) incl += v;
    }
    unsigned total = __shfl(incl, 63);
    if (total >= 17u) {
      unsigned base = incl - s4;
      bool has = (incl >= 17u) && (base < 17u);
      u64 hmask = __ballot(has);
      int srcl = __ffsll((unsigned long long)hmask) - 1;
      int bl = 0; unsigned Cl = 0;
      if (has) {
        if (base + cv.x >= 17u)                    { bl = lane*4 + 0; Cl = base; }
        else if (base + cv.x + cv.y >= 17u)        { bl = lane*4 + 1; Cl = base + cv.x; }
        else if (base + cv.x + cv.y + cv.z >= 17u) { bl = lane*4 + 2; Cl = base + cv.x + cv.y; }
        else                                       { bl = lane*4 + 3; Cl = base + cv.x + cv.y + cv.z; }
      }
      bstar = __shfl(bl, srcl);
      C     = __shfl(Cl, srcl);
      break;
    }
    scale *= 0.25f;
  }
  const int m = 17 - (int)C;

  u64 lst[6];
  #pragma unroll
  for (int t = 0; t < 6; t++) lst[t] = ~0ull;
  #pragma unroll
  for (int t = 0; t < 32; t++) {
    int bin = (int)(d[t] * scale);
    u64 key = ((u64)__float_as_uint(d[t]) << 11) | (unsigned)(t * 64 + lane);
    u64 cand = (bin == bstar) ? key : ~0ull;
    if (cand < lst[5]) {
      lst[5] = cand;
      #pragma unroll
      for (int u = 5; u > 0; u--) {
        u64 a = lst[u-1], c2 = lst[u];
        lst[u-1] = a < c2 ? a : c2;
        lst[u]   = a < c2 ? c2 : a;
      }
    }
  }

  u64 kstar = 0;
  #pragma unroll 1
  for (int r = 0; r < m; r++) {
    u64 h0 = lst[0];
    u64 gm = wave_min_u64(h0);
    kstar = gm;
    bool win = (h0 == gm);
    #pragma unroll
    for (int u = 0; u < 5; u++) lst[u] = win ? lst[u+1] : lst[u];
    lst[5] = win ? ~0ull : lst[5];
  }

  int* outp = nbr + ((size_t)b * NN + i) * KK;
  int total = 0;
  #pragma unroll
  for (int t = 0; t < 32; t++) {
    int j = t * 64 + lane;
    u64 key = ((u64)__float_as_uint(d[t]) << 11) | (unsigned)j;
    bool pred = (key <= kstar) && (j != i);
    u64 msk = __ballot(pred);
    if (pred) {
      int ofs = total + __popcll(msk & ((1ull << lane) - 1ull));
      outp[ofs] = b * NN + j;
      atomicAdd(&cnt[b * NN + j], 1);
    }
    total += __popcll(msk);
  }
}

// ---------------- CSR build ----------------
__global__ __launch_bounds__(256) void scan_kernel(const int* __restrict__ cnt,
                                                   int* __restrict__ row_ptr) {
  __shared__ int ps[256];
  int t = threadIdx.x;
  const int4* cv = (const int4*)(cnt + t * 64);
  int4 c[16];
  int s = 0;
  #pragma unroll
  for (int i = 0; i < 16; i++) {
    c[i] = cv[i];
    s += c[i].x + c[i].y + c[i].z + c[i].w;
  }
  ps[t] = s;
  __syncthreads();
  for (int off = 1; off < 256; off <<= 1) {
    int v = 0;
    if (t >= off) v = ps[t - off];
    __syncthreads();
    ps[t] += v;
    __syncthreads();
  }
  int run = t ? ps[t - 1] : 0;
  int4* rp = (int4*)(row_ptr + t * 64);
  #pragma unroll
  for (int i = 0; i < 16; i++) {
    int4 o;
    o.x = run; run += c[i].x;
    o.y = run; run += c[i].y;
    o.z = run; run += c[i].z;
    o.w = run; run += c[i].w;
    rp[i] = o;
  }
  if (t == 255) row_ptr[BN] = run;
}

__global__ __launch_bounds__(256) void fill_kernel(const int* __restrict__ nbr,
                                                   const int* __restrict__ row_ptr,
                                                   int* __restrict__ fill,
                                                   int* __restrict__ col) {
  int e = blockIdx.x * 256 + threadIdx.x;
  int d = nbr[e];
  int srcn = e >> 4;
  int p = row_ptr[d] + atomicAdd(&fill[d], 1);
  col[p] = srcn;
}

// ================= split-bf16 MFMA machinery (round-9, verified) =========
// 3-term split a*b ~= ah*bh + ah*bl + al*bh, rel err ~1e-5.
// Fragment map (pi-consistent A/B): chunk(row,kg) holds k = kg*8..kg*8+7 at
// idx = (((row>>4)*4 + (kg>>2))*64 + ((row&15)|((kg&3)<<4)))*8.
// D layout (HW-verified): col = lane&15, row = (lane>>4)*4 + reg.

__device__ __forceinline__ ushort_t bf16_rne(float x) {
  unsigned u = __float_as_uint(x);
  unsigned r = u + 0x7FFFu + ((u >> 16) & 1u);
  return (ushort_t)(r >> 16);
}
__device__ __forceinline__ float bf16_to_f(ushort_t h) {
  return __uint_as_float(((unsigned)h) << 16);
}

__device__ __forceinline__ void cvt8(const float4 f0, const float4 f1,
                                     short8& hi, short8& lo) {
  float f[8] = {f0.x, f0.y, f0.z, f0.w, f1.x, f1.y, f1.z, f1.w};
  #pragma unroll
  for (int e = 0; e < 8; e++) {
    ushort_t h = bf16_rne(f[e]);
    ushort_t l = bf16_rne(f[e] - bf16_to_f(h));
    hi[e] = (short)h;
    lo[e] = (short)l;
  }
}

// prep: 16 unit-Ws (128x128) -> fragment-ordered bf16 hi/lo (unchanged r9)
__global__ __launch_bounds__(256) void prep_w_kernel(
    const float* __restrict__ enc_w1, const float* __restrict__ msg_w,
    const float* __restrict__ upd_w, const float* __restrict__ proj_w0,
    const float* __restrict__ proj_w1, ushort_t* __restrict__ wfrag) {
  int u = blockIdx.x >> 3;
  int c = (blockIdx.x & 7) * 256 + threadIdx.x;
  const float* src;
  int ldW = HID;
  if (u == 0) src = enc_w1;
  else if (u <= 6)  { int i = (u-1)>>1; int hf = (u-1)&1; src = msg_w + ((size_t)i*256 + hf*128) * HID; }
  else if (u <= 12) { int i = (u-7)>>1; int hf = (u-7)&1; src = upd_w + ((size_t)i*256 + hf*128) * HID; }
  else if (u == 13) src = proj_w0;
  else { src = proj_w1 + (u - 14) * 128; ldW = PROJ_D; }

  int ks = c >> 9, ct = (c >> 6) & 7, lane = c & 63;
  int colc = ct * 16 + (lane & 15);
  int k0 = ks * 32 + ((lane >> 4) << 3);
  float f[8];
  #pragma unroll
  for (int e = 0; e < 8; e++) f[e] = src[(size_t)(k0 + e) * ldW + colc];
  short8 hv, lv;
  cvt8(make_float4(f[0],f[1],f[2],f[3]), make_float4(f[4],f[5],f[6],f[7]), hv, lv);
  *(short8*)&wfrag[(size_t)u * 32768 + (size_t)c * 8] = hv;
  *(short8*)&wfrag[(size_t)u * 32768 + 16384 + (size_t)c * 8] = lv;
}

// ---- building blocks ----
__device__ __forceinline__ void zacc(f32x4 acc[8]) {
  f32x4 z = {0.f, 0.f, 0.f, 0.f};
  #pragma unroll
  for (int ct = 0; ct < 8; ct++) acc[ct] = z;
}

// linear copy of pre-converted fragments (producer-side conversion)
__device__ __forceinline__ void stage_A_linear(ushort_t* Ahi, ushort_t* Alo,
                                               const ushort_t* gfrag, int tid) {
  const short8* gh = (const short8*)gfrag;
  const short8* gl = (const short8*)(gfrag + 8192);
  #pragma unroll
  for (int i = 0; i < 4; i++) {
    ((short8*)Ahi)[tid + i * 256] = gh[tid + i * 256];
    ((short8*)Alo)[tid + i * 256] = gl[tid + i * 256];
  }
}

// convert 64x128 f32 global rows -> fragment hi/lo in LDS (consumer-side)
__device__ __forceinline__ void stage_A_convert(ushort_t* Ahi, ushort_t* Alo,
                                                const float* A, int m0, int tid) {
  #pragma unroll
  for (int i = 0; i < 4; i++) {
    int c = tid + i * 256;
    int row = c >> 4, kg = c & 15;
    const float4* ap = (const float4*)(A + (((size_t)m0 + row) << 7) + (kg << 3));
    short8 hv, lv;
    cvt8(ap[0], ap[1], hv, lv);
    int idx = (((row >> 4) * 4 + (kg >> 2)) * 64 + ((row & 15) | ((kg & 3) << 4))) * 8;
    *(short8*)&Ahi[idx] = hv;
    *(short8*)&Alo[idx] = lv;
  }
}

// convert 64x128 f32 LDS tile -> fragment hi/lo in LDS
__device__ __forceinline__ void ldsF_to_frags(const float* ldsF,
                                              ushort_t* Ahi, ushort_t* Alo,
                                              int tid) {
  #pragma unroll
  for (int i = 0; i < 4; i++) {
    int c = tid + i * 256;
    int row = c >> 4, kg = c & 15;
    const float4* ap = (const float4*)&ldsF[row * 128 + kg * 8];
    short8 hv, lv;
    cvt8(ap[0], ap[1], hv, lv);
    int idx = (((row >> 4) * 4 + (kg >> 2)) * 64 + ((row & 15) | ((kg & 3) << 4))) * 8;
    *(short8*)&Ahi[idx] = hv;
    *(short8*)&Alo[idx] = lv;
  }
}

// emit 64x128 f32 LDS tile -> global frags (+ optional f32 copies, coalesced)
__device__ __forceinline__ void ldsF_emit(const float* ldsF,
                                          ushort_t* gfrag, float* gf32,
                                          float* gf32b, int tid) {
  #pragma unroll
  for (int i = 0; i < 4; i++) {
    int c = tid + i * 256;
    int row = c >> 4, kg = c & 15;
    const float4* ap = (const float4*)&ldsF[row * 128 + kg * 8];
    float4 a0 = ap[0], a1 = ap[1];
    short8 hv, lv;
    cvt8(a0, a1, hv, lv);
    int idx = (((row >> 4) * 4 + (kg >> 2)) * 64 + ((row & 15) | ((kg & 3) << 4))) * 8;
    *(short8*)&gfrag[idx] = hv;
    *(short8*)&gfrag[8192 + idx] = lv;
    if (gf32) {
      float4* op = (float4*)&gf32[(size_t)row * 128 + kg * 8];
      op[0] = a0; op[1] = a1;
    }
    if (gf32b) {
      float4* op = (float4*)&gf32b[(size_t)row * 128 + kg * 8];
      op[0] = a0; op[1] = a1;
    }
  }
}

// one 128x128 unit: acc += A @ W (B staged in halves; leading barrier protects
// Bhi/Blo reuse AND makes prior Ahi/Alo writes visible)
__device__ __forceinline__ void unit_mfma(f32x4 acc[8], const ushort_t* wf,
                                          const ushort_t* Ahi, const ushort_t* Alo,
                                          ushort_t* Bhi, ushort_t* Blo,
                                          int tid, int lane, int wid) {
  #pragma unroll 1
  for (int half = 0; half < 2; half++) {
    __syncthreads();
    const short8* ghi = (const short8*)(wf + half * 8192);
    const short8* glo = (const short8*)(wf + 16384 + half * 8192);
    #pragma unroll
    for (int i = 0; i < 4; i++) {
      ((short8*)Bhi)[tid + i * 256] = ghi[tid + i * 256];
      ((short8*)Blo)[tid + i * 256] = glo[tid + i * 256];
    }
    __syncthreads();
    #pragma unroll
    for (int ks2 = 0; ks2 < 2; ks2++) {
      int ksA = half * 2 + ks2;
      short8 ah = *(const short8*)&Ahi[((wid * 4 + ksA) * 64 + lane) * 8];
      short8 al = *(const short8*)&Alo[((wid * 4 + ksA) * 64 + lane) * 8];
      #pragma unroll
      for (int ct = 0; ct < 8; ct++) {
        short8 bh = *(const short8*)&Bhi[((ks2 * 8 + ct) * 64 + lane) * 8];
        short8 bl = *(const short8*)&Blo[((ks2 * 8 + ct) * 64 + lane) * 8];
        acc[ct] = __builtin_amdgcn_mfma_f32_16x16x32_bf16(ah, bh, acc[ct], 0, 0, 0);
        acc[ct] = __builtin_amdgcn_mfma_f32_16x16x32_bf16(ah, bl, acc[ct], 0, 0, 0);
        acc[ct] = __builtin_amdgcn_mfma_f32_16x16x32_bf16(al, bh, acc[ct], 0, 0, 0);
      }
    }
  }
}

// epilogue: scattered f32 store (for agg inputs / final z)
__device__ __forceinline__ void epi_store_f32(const f32x4 acc[8], const float* bias,
                                              float* out, int ldOut, int n0,
                                              int m0, int lane, int wid) {
  int rbase = m0 + wid * 16 + ((lane >> 4) << 2);
  int cb = lane & 15;
  #pragma unroll
  for (int ct = 0; ct < 8; ct++) {
    int n = n0 + ct * 16 + cb;
    float bv = bias ? bias[n] : 0.f;
    #pragma unroll
    for (int r = 0; r < 4; r++)
      out[(size_t)(rbase + r) * ldOut + n] = acc[ct][r] + bv;
  }
}

// epilogue: relu(acc+bias) [+Res] -> LDS f32 tile (for frag emission)
__device__ __forceinline__ void epi_to_ldsF(const f32x4 acc[8], const float* bias,
                                            float* ldsF, int lane, int wid,
                                            const float* Res, int m0) {
  int rloc = wid * 16 + ((lane >> 4) << 2);
  int cb = lane & 15;
  #pragma unroll
  for (int ct = 0; ct < 8; ct++) {
    int n = ct * 16 + cb;
    float bv = bias ? bias[n] : 0.f;
    #pragma unroll
    for (int r = 0; r < 4; r++) {
      float v = fmaxf(acc[ct][r] + bv, 0.f);
      if (Res) v += Res[(size_t)(m0 + rloc + r) * HID + n];
      ldsF[(rloc + r) * 128 + n] = v;
    }
  }
}

#define LDS_DECL \
  __shared__ char LDSBUF[65536]; \
  ushort_t* Ahi = (ushort_t*)LDSBUF; \
  ushort_t* Alo = (ushort_t*)(LDSBUF + 16384); \
  ushort_t* Bhi = (ushort_t*)(LDSBUF + 32768); \
  ushort_t* Blo = (ushort_t*)(LDSBUF + 49152); \
  float* ldsF = (float*)(LDSBUF + 32768); \
  const int tid = threadIdx.x, lane = tid & 63, wid = tid >> 6; \
  const int m0 = blockIdx.x * 64;

// ---------------- K1: enc0 + enc1, emits h f32 + h fragments ----------------
__global__ __launch_bounds__(256, 2) void encg1_kernel(
    const float* __restrict__ x, const float* __restrict__ ew0,
    const float* __restrict__ eb0, const ushort_t* __restrict__ wf_enc1,
    const float* __restrict__ eb1, float* __restrict__ hF32,
    ushort_t* __restrict__ hfrag) {
  LDS_DECL
  float* XWs = (float*)LDSBUF;   // overlay on Ahi/Alo (needs < 4 KB)
  const int tx = tid & 31, ty = tid >> 5;

  if (tid < 80) ((float4*)XWs)[tid] = ((const float4*)(x + (size_t)m0 * 5))[tid];
  if (tid < 160) ((float4*)(XWs + 320))[tid] = ((const float4*)ew0)[tid];
  __syncthreads();
  {
    float4 bv = *(const float4*)&eb0[tx * 4];
    #pragma unroll
    for (int r = 0; r < 8; r++) {
      int row = ty + r * 8;
      float4 a = bv;
      #pragma unroll
      for (int d = 0; d < 5; d++) {
        float xv = XWs[row * 5 + d];
        float4 w = *(const float4*)&XWs[320 + d * 128 + tx * 4];
        a.x += xv*w.x; a.y += xv*w.y; a.z += xv*w.z; a.w += xv*w.w;
      }
      a.x = fmaxf(a.x,0.f); a.y = fmaxf(a.y,0.f);
      a.z = fmaxf(a.z,0.f); a.w = fmaxf(a.w,0.f);
      *(float4*)&ldsF[row * 128 + tx * 4] = a;
    }
  }
  __syncthreads();
  ldsF_to_frags(ldsF, Ahi, Alo, tid);    // XWs dead; ldsF consumed by this
  f32x4 acc[8];
  zacc(acc);
  unit_mfma(acc, wf_enc1, Ahi, Alo, Bhi, Blo, tid, lane, wid);
  __syncthreads();                        // B reads done before ldsF overwrite
  epi_to_ldsF(acc, eb1, ldsF, lane, wid, nullptr, m0);
  __syncthreads();
  ldsF_emit(ldsF, hfrag + (size_t)blockIdx.x * 16384,
            hF32 + (size_t)m0 * HID, nullptr, tid);
}

// ---------------- msg pair: bufA = h@Wt ; bufB = h@Wb + mb (one kernel) -----
__global__ __launch_bounds__(256, 2) void msg_kernel(
    const ushort_t* __restrict__ hfrag, const ushort_t* __restrict__ wfT,
    const ushort_t* __restrict__ wfB, const float* __restrict__ mb,
    float* __restrict__ bufA, float* __restrict__ bufB) {
  LDS_DECL
  stage_A_linear(Ahi, Alo, hfrag + (size_t)blockIdx.x * 16384, tid);
  f32x4 acc[8];
  zacc(acc);
  unit_mfma(acc, wfT, Ahi, Alo, Bhi, Blo, tid, lane, wid);
  epi_store_f32(acc, nullptr, bufA, HID, 0, m0, lane, wid);
  zacc(acc);
  unit_mfma(acc, wfB, Ahi, Alo, Bhi, Blo, tid, lane, wid);
  epi_store_f32(acc, mb, bufB, HID, 0, m0, lane, wid);
}

// ---------------- upd: h' = h + relu(h@Wt + agg@Wb + ub); emits frags ------
__global__ __launch_bounds__(256, 2) void upd_kernel(
    const ushort_t* __restrict__ hfrag_cur, const ushort_t* __restrict__ wuT,
    const float* __restrict__ aggF, const ushort_t* __restrict__ wuB,
    const float* __restrict__ ub, float* __restrict__ hF32,
    ushort_t* __restrict__ hfrag_nxt, float* __restrict__ hOutOpt) {
  LDS_DECL
  stage_A_linear(Ahi, Alo, hfrag_cur + (size_t)blockIdx.x * 16384, tid);
  f32x4 acc[8];
  zacc(acc);
  unit_mfma(acc, wuT, Ahi, Alo, Bhi, Blo, tid, lane, wid);
  __syncthreads();                        // phase-1 A reads done
  stage_A_convert(Ahi, Alo, aggF, m0, tid);
  unit_mfma(acc, wuB, Ahi, Alo, Bhi, Blo, tid, lane, wid);
  __syncthreads();                        // B reads done before ldsF overwrite
  epi_to_ldsF(acc, ub, ldsF, lane, wid, hF32, m0);
  __syncthreads();
  ldsF_emit(ldsF, hfrag_nxt + (size_t)blockIdx.x * 16384,
            hF32 + (size_t)m0 * HID,
            hOutOpt ? hOutOpt + (size_t)m0 * HID : nullptr, tid);
}

// ---------------- proj: z = relu(h@p0 + b0) @ p1 + b1 (fused) ---------------
__global__ __launch_bounds__(256, 2) void proj_kernel(
    const ushort_t* __restrict__ hfrag, const ushort_t* __restrict__ wf0,
    const float* __restrict__ pb0, const ushort_t* __restrict__ wf1,
    const float* __restrict__ pb1, float* __restrict__ z) {
  LDS_DECL
  stage_A_linear(Ahi, Alo, hfrag + (size_t)blockIdx.x * 16384, tid);
  f32x4 acc[8];
  zacc(acc);
  unit_mfma(acc, wf0, Ahi, Alo, Bhi, Blo, tid, lane, wid);
  __syncthreads();
  epi_to_ldsF(acc, pb0, ldsF, lane, wid, nullptr, m0);
  __syncthreads();
  ldsF_to_frags(ldsF, Ahi, Alo, tid);     // proj0 A consumed; overwrite
  #pragma unroll 1
  for (int y = 0; y < 2; y++) {
    zacc(acc);
    unit_mfma(acc, wf1 + (size_t)y * 32768, Ahi, Alo, Bhi, Blo, tid, lane, wid);
    epi_store_f32(acc, pb1, z, PROJ_D, y * 128, m0, lane, wid);
  }
}

// ---------------- fused message + mean-aggregation (2 nodes/block) --------
__global__ __launch_bounds__(256) void agg_kernel(const float* __restrict__ Abuf,
                                                  const float* __restrict__ Bbuf,
                                                  const int* __restrict__ row_ptr,
                                                  const int* __restrict__ col,
                                                  float* __restrict__ agg) {
  int j = blockIdx.x * 2 + (threadIdx.x >> 7);
  int c = threadIdx.x & 127;
  float bj = Bbuf[(size_t)j * HID + c];
  int s = row_ptr[j], e = row_ptr[j + 1];
  float acc = 0.f;
  int p = s;
  for (; p + 4 <= e; p += 4) {
    int i0 = col[p], i1 = col[p+1], i2 = col[p+2], i3 = col[p+3];
    float v0 = Abuf[(size_t)i0 * HID + c];
    float v1 = Abuf[(size_t)i1 * HID + c];
    float v2 = Abuf[(size_t)i2 * HID + c];
    float v3 = Abuf[(size_t)i3 * HID + c];
    acc += fmaxf(v0 + bj, 0.f) + fmaxf(v1 + bj, 0.f)
         + fmaxf(v2 + bj, 0.f) + fmaxf(v3 + bj, 0.f);
  }
  for (; p < e; p++) {
    int i = col[p];
    acc += fmaxf(Abuf[(size_t)i * HID + c] + bj, 0.f);
  }
  float deg = (float)(e - s);
  float inv = 1.0f / fmaxf(deg, 1.0f);
  agg[(size_t)j * HID + c] = acc * inv;
}

extern "C" void kernel_launch(void* const* d_in, const int* in_sizes, int n_in,
                              void* d_out, int out_size, void* d_ws, size_t ws_size,
                              hipStream_t stream) {
  (void)in_sizes; (void)n_in; (void)out_size; (void)ws_size;
  const float* x       = (const float*)d_in[0];
  const float* pos     = (const float*)d_in[1];
  const float* enc_w0  = (const float*)d_in[3];
  const float* enc_b0  = (const float*)d_in[4];
  const float* enc_w1  = (const float*)d_in[5];
  const float* enc_b1  = (const float*)d_in[6];
  const float* msg_w   = (const float*)d_in[7];
  const float* msg_b   = (const float*)d_in[8];
  const float* upd_w   = (const float*)d_in[9];
  const float* upd_b   = (const float*)d_in[10];
  const float* proj_w0 = (const float*)d_in[11];
  const float* proj_b0 = (const float*)d_in[12];
  const float* proj_w1 = (const float*)d_in[13];
  const float* proj_b1 = (const float*)d_in[14];

  char* ws = (char*)d_ws;
  size_t off = 0;
  auto alloc = [&](size_t bytes) -> void* {
    void* p = ws + off;
    off += (bytes + 255) & ~(size_t)255;
    return p;
  };
  int*      nbr      = (int*)alloc((size_t)EE * 4);
  int*      cnt      = (int*)alloc((size_t)BN * 4);
  int*      fill     = (int*)alloc((size_t)BN * 4);
  int*      row_ptr  = (int*)alloc((size_t)(BN + 1) * 4);
  int*      col      = (int*)alloc((size_t)EE * 4);
  float*    h        = (float*)alloc((size_t)BN * HID * 4);
  float*    bufA     = (float*)alloc((size_t)BN * HID * 4);
  float*    bufB     = (float*)alloc((size_t)BN * HID * 4);
  float*    bufAgg   = (float*)alloc((size_t)BN * HID * 4);
  ushort_t* wfrag    = (ushort_t*)alloc((size_t)16 * 32768 * 2);
  ushort_t* hfrag_a  = (ushort_t*)alloc((size_t)256 * 16384 * 2);
  ushort_t* hfrag_b  = (ushort_t*)alloc((size_t)256 * 16384 * 2);
  float*    out      = (float*)d_out;
  float*    hOut     = out + (size_t)BN * PROJ_D;

  hipMemsetAsync(cnt, 0, (size_t)BN * 4 * 2, stream);   // cnt + fill

  prep_w_kernel<<<128, 256, 0, stream>>>(enc_w1, msg_w, upd_w, proj_w0, proj_w1, wfrag);
  knn_kernel<<<BN / QPB, 1024, 0, stream>>>(pos, nbr, cnt);
  scan_kernel<<<1, 256, 0, stream>>>(cnt, row_ptr);
  fill_kernel<<<EE / 256, 256, 0, stream>>>(nbr, row_ptr, fill, col);

  encg1_kernel<<<BN / 64, 256, 0, stream>>>(x, enc_w0, enc_b0, wfrag,
                                            enc_b1, h, hfrag_a);

  ushort_t* fcur = hfrag_a;
  ushort_t* fnxt = hfrag_b;
  for (int i = 0; i < 3; i++) {
    msg_kernel<<<BN / 64, 256, 0, stream>>>(
        fcur, wfrag + (size_t)(1 + 2 * i) * 32768,
        wfrag + (size_t)(2 + 2 * i) * 32768, msg_b + (size_t)i * HID,
        bufA, bufB);
    agg_kernel<<<BN / 2, 256, 0, stream>>>(bufA, bufB, row_ptr, col, bufAgg);
    upd_kernel<<<BN / 64, 256, 0, stream>>>(
        fcur, wfrag + (size_t)(7 + 2 * i) * 32768, bufAgg,
        wfrag + (size_t)(8 + 2 * i) * 32768, upd_b + (size_t)i * HID,
        h, fnxt, (i == 2) ? hOut : nullptr);
    ushort_t* t = fcur; fcur = fnxt; fnxt = t;
  }

  proj_kernel<<<BN / 64, 256, 0, stream>>>(
      fcur, wfrag + (size_t)13 * 32768, proj_b0,
      wfrag + (size_t)14 * 32768, proj_b1, out);
}

// Round 11
// 241.930 us; speedup vs baseline: 1.1297x; 1.1297x over previous
//
#include <hip/hip_runtime.h>
#include <stdint.h>
#include <math.h>

#define NN 2048
#define BB 8
#define BN (BB*NN)
#define KK 16
#define EE (BN*KK)
#define HID 128
#define PROJ_D 256
#define QPB 16   // queries (waves) per knn block

typedef unsigned long long u64;
typedef unsigned short ushort_t;
typedef __attribute__((ext_vector_type(8))) short short8;
typedef __attribute__((ext_vector_type(4))) float f32x4;

__device__ __forceinline__ u64 wave_min_u64(u64 v) {
  #pragma unroll
  for (int off = 32; off > 0; off >>= 1) {
    u64 o = __shfl_xor(v, off);
    v = o < v ? o : v;
  }
  return v;
}

// ---------------- kNN + fused degree count (round-5/6 design, unchanged) ----
__global__ __launch_bounds__(1024) void knn_kernel(const float* __restrict__ pos,
                                                   int* __restrict__ nbr,
                                                   int* __restrict__ cnt) {
  __shared__ float4 Ps[NN];
  __shared__ unsigned Hist[QPB * 256];
  const int b  = blockIdx.x >> 7;
  const int qb = blockIdx.x & 127;
  const int wave = threadIdx.x >> 6;
  const int lane = threadIdx.x & 63;
  const int i = qb * QPB + wave;
  const float* P = pos + (size_t)b * NN * 3;

  for (int t = threadIdx.x; t < NN; t += 1024)
    Ps[t] = make_float4(P[t*3], P[t*3+1], P[t*3+2], 0.f);
  __syncthreads();

  const float4 pi = Ps[i];
  const float xi = pi.x, yi = pi.y, zi = pi.z;
  unsigned* H = &Hist[wave * 256];

  float d[32];
  #pragma unroll
  for (int t = 0; t < 32; t++) {
    int j = t * 64 + lane;
    float4 pj = Ps[j];
    float ax = fabsf(xi - pj.x), ay = fabsf(yi - pj.y), az = fabsf(zi - pj.z);
    float dx = fminf(ax, 1.0f - ax);
    float dy = fminf(ay, 1.0f - ay);
    float dz = fminf(az, 1.0f - az);
    float s = __fadd_rn(__fadd_rn(__fadd_rn(__fmul_rn(dx,dx), __fmul_rn(dy,dy)),
                                  __fmul_rn(dz,dz)), 1e-12f);
    d[t] = __fsqrt_rn(s);
  }

  float scale = 1024.0f;
  int bstar = 0; unsigned C = 0;
  for (;;) {
    *(uint4*)&H[lane * 4] = make_uint4(0u, 0u, 0u, 0u);
    #pragma unroll
    for (int t = 0; t < 32; t++) {
      int bin = (int)(d[t] * scale);
      if (bin < 256) atomicAdd(&H[bin], 1u);
    }
    uint4 cv = *(const uint4*)&H[lane * 4];
    unsigned s4 = cv.x + cv.y + cv.z + cv.w;
    unsigned incl = s4;
    #pragma unroll
    for (int off = 1; off < 64; off <<= 1) {
      unsigned v = __shfl_up(incl, off);
      if (lane >= off) incl += v;
    }
    unsigned total = __shfl(incl, 63);
    if (total >= 17u) {
      unsigned base = incl - s4;
      bool has = (incl >= 17u) && (base < 17u);
      u64 hmask = __ballot(has);
      int srcl = __ffsll((unsigned long long)hmask) - 1;
      int bl = 0; unsigned Cl = 0;
      if (has) {
        if (base + cv.x >= 17u)                    { bl = lane*4 + 0; Cl = base; }
        else if (base + cv.x + cv.y >= 17u)        { bl = lane*4 + 1; Cl = base + cv.x; }
        else if (base + cv.x + cv.y + cv.z >= 17u) { bl = lane*4 + 2; Cl = base + cv.x + cv.y; }
        else                                       { bl = lane*4 + 3; Cl = base + cv.x + cv.y + cv.z; }
      }
      bstar = __shfl(bl, srcl);
      C     = __shfl(Cl, srcl);
      break;
    }
    scale *= 0.25f;
  }
  const int m = 17 - (int)C;

  u64 lst[6];
  #pragma unroll
  for (int t = 0; t < 6; t++) lst[t] = ~0ull;
  #pragma unroll
  for (int t = 0; t < 32; t++) {
    int bin = (int)(d[t] * scale);
    u64 key = ((u64)__float_as_uint(d[t]) << 11) | (unsigned)(t * 64 + lane);
    u64 cand = (bin == bstar) ? key : ~0ull;
    if (cand < lst[5]) {
      lst[5] = cand;
      #pragma unroll
      for (int u = 5; u > 0; u--) {
        u64 a = lst[u-1], c2 = lst[u];
        lst[u-1] = a < c2 ? a : c2;
        lst[u]   = a < c2 ? c2 : a;
      }
    }
  }

  u64 kstar = 0;
  #pragma unroll 1
  for (int r = 0; r < m; r++) {
    u64 h0 = lst[0];
    u64 gm = wave_min_u64(h0);
    kstar = gm;
    bool win = (h0 == gm);
    #pragma unroll
    for (int u = 0; u < 5; u++) lst[u] = win ? lst[u+1] : lst[u];
    lst[5] = win ? ~0ull : lst[5];
  }

  int* outp = nbr + ((size_t)b * NN + i) * KK;
  int total = 0;
  #pragma unroll
  for (int t = 0; t < 32; t++) {
    int j = t * 64 + lane;
    u64 key = ((u64)__float_as_uint(d[t]) << 11) | (unsigned)j;
    bool pred = (key <= kstar) && (j != i);
    u64 msk = __ballot(pred);
    if (pred) {
      int ofs = total + __popcll(msk & ((1ull << lane) - 1ull));
      outp[ofs] = b * NN + j;
      atomicAdd(&cnt[b * NN + j], 1);
    }
    total += __popcll(msk);
  }
}

// ---------------- CSR build ----------------
__global__ __launch_bounds__(256) void scan_kernel(const int* __restrict__ cnt,
                                                   int* __restrict__ row_ptr) {
  __shared__ int ps[256];
  int t = threadIdx.x;
  const int4* cv = (const int4*)(cnt + t * 64);
  int4 c[16];
  int s = 0;
  #pragma unroll
  for (int i = 0; i < 16; i++) {
    c[i] = cv[i];
    s += c[i].x + c[i].y + c[i].z + c[i].w;
  }
  ps[t] = s;
  __syncthreads();
  for (int off = 1; off < 256; off <<= 1) {
    int v = 0;
    if (t >= off) v = ps[t - off];
    __syncthreads();
    ps[t] += v;
    __syncthreads();
  }
  int run = t ? ps[t - 1] : 0;
  int4* rp = (int4*)(row_ptr + t * 64);
  #pragma unroll
  for (int i = 0; i < 16; i++) {
    int4 o;
    o.x = run; run += c[i].x;
    o.y = run; run += c[i].y;
    o.z = run; run += c[i].z;
    o.w = run; run += c[i].w;
    rp[i] = o;
  }
  if (t == 255) row_ptr[BN] = run;
}

__global__ __launch_bounds__(256) void fill_kernel(const int* __restrict__ nbr,
                                                   const int* __restrict__ row_ptr,
                                                   int* __restrict__ fill,
                                                   int* __restrict__ col) {
  int e = blockIdx.x * 256 + threadIdx.x;
  int d = nbr[e];
  int srcn = e >> 4;
  int p = row_ptr[d] + atomicAdd(&fill[d], 1);
  col[p] = srcn;
}

// ---------------- encoder layer 0: (BN,5)@(5,128)+relu ----------------
__global__ __launch_bounds__(256) void enc0_kernel(const float* __restrict__ x,
                                                   const float* __restrict__ w0,
                                                   const float* __restrict__ b0,
                                                   float* __restrict__ h) {
  int t = blockIdx.x * 256 + threadIdx.x;
  int m = t >> 5;
  int c = (t & 31) * 4;
  float xv[5];
  #pragma unroll
  for (int d = 0; d < 5; d++) xv[d] = x[m * 5 + d];
  float4 acc = *(const float4*)&b0[c];
  #pragma unroll
  for (int d = 0; d < 5; d++) {
    float4 w = *(const float4*)&w0[d * HID + c];
    acc.x += xv[d] * w.x; acc.y += xv[d] * w.y;
    acc.z += xv[d] * w.z; acc.w += xv[d] * w.w;
  }
  acc.x = fmaxf(acc.x, 0.f); acc.y = fmaxf(acc.y, 0.f);
  acc.z = fmaxf(acc.z, 0.f); acc.w = fmaxf(acc.w, 0.f);
  *(float4*)&h[(size_t)m * HID + c] = acc;
}

// ================= split-bf16 MFMA machinery (round-9, verified) =========
// 3-term split a*b ~= ah*bh + ah*bl + al*bh, rel err ~1e-5.
// Fragment map (pi-consistent A/B): chunk(row,kg) holds k = kg*8..kg*8+7 at
// idx = (((row>>4)*4 + (kg>>2))*64 + ((row&15)|((kg&3)<<4)))*8.
// W-frag chunk index c = ks*512 + ct*64 + lane (ks: kstep of 32, ct: 16-col tile).
// D layout (HW-verified): col = lane&15, row = (lane>>4)*4 + reg.
// Round-11: N-split (ct0 = 0 or 4) so g1/upd run at grid 512 = full machine.

__device__ __forceinline__ ushort_t bf16_rne(float x) {
  unsigned u = __float_as_uint(x);
  unsigned r = u + 0x7FFFu + ((u >> 16) & 1u);
  return (ushort_t)(r >> 16);
}
__device__ __forceinline__ float bf16_to_f(ushort_t h) {
  return __uint_as_float(((unsigned)h) << 16);
}

__device__ __forceinline__ void cvt8(const float4 f0, const float4 f1,
                                     short8& hi, short8& lo) {
  float f[8] = {f0.x, f0.y, f0.z, f0.w, f1.x, f1.y, f1.z, f1.w};
  #pragma unroll
  for (int e = 0; e < 8; e++) {
    ushort_t h = bf16_rne(f[e]);
    ushort_t l = bf16_rne(f[e] - bf16_to_f(h));
    hi[e] = (short)h;
    lo[e] = (short)l;
  }
}

// prep: 16 unit-Ws (128x128) -> fragment-ordered bf16 hi/lo (unchanged r9)
__global__ __launch_bounds__(256) void prep_w_kernel(
    const float* __restrict__ enc_w1, const float* __restrict__ msg_w,
    const float* __restrict__ upd_w, const float* __restrict__ proj_w0,
    const float* __restrict__ proj_w1, ushort_t* __restrict__ wfrag) {
  int u = blockIdx.x >> 3;
  int c = (blockIdx.x & 7) * 256 + threadIdx.x;
  const float* src;
  int ldW = HID;
  if (u == 0) src = enc_w1;
  else if (u <= 6)  { int i = (u-1)>>1; int hf = (u-1)&1; src = msg_w + ((size_t)i*256 + hf*128) * HID; }
  else if (u <= 12) { int i = (u-7)>>1; int hf = (u-7)&1; src = upd_w + ((size_t)i*256 + hf*128) * HID; }
  else if (u == 13) src = proj_w0;
  else { src = proj_w1 + (u - 14) * 128; ldW = PROJ_D; }

  int ks = c >> 9, ct = (c >> 6) & 7, lane = c & 63;
  int colc = ct * 16 + (lane & 15);
  int k0 = ks * 32 + ((lane >> 4) << 3);
  float f[8];
  #pragma unroll
  for (int e = 0; e < 8; e++) f[e] = src[(size_t)(k0 + e) * ldW + colc];
  short8 hv, lv;
  cvt8(make_float4(f[0],f[1],f[2],f[3]), make_float4(f[4],f[5],f[6],f[7]), hv, lv);
  *(short8*)&wfrag[(size_t)u * 32768 + (size_t)c * 8] = hv;
  *(short8*)&wfrag[(size_t)u * 32768 + 16384 + (size_t)c * 8] = lv;
}

// convert 64x128 f32 global rows -> fragment hi/lo in LDS (consumer-side)
__device__ __forceinline__ void stage_A_convert(ushort_t* Ahi, ushort_t* Alo,
                                                const float* A, int m0, int tid) {
  #pragma unroll
  for (int i = 0; i < 4; i++) {
    int c = tid + i * 256;
    int row = c >> 4, kg = c & 15;
    const float4* ap = (const float4*)(A + (((size_t)m0 + row) << 7) + (kg << 3));
    short8 hv, lv;
    cvt8(ap[0], ap[1], hv, lv);
    int idx = (((row >> 4) * 4 + (kg >> 2)) * 64 + ((row & 15) | ((kg & 3) << 4))) * 8;
    *(short8*)&Ahi[idx] = hv;
    *(short8*)&Alo[idx] = lv;
  }
}

// ---- full-N unit (8 col-tiles), r9-verified ----
__device__ __forceinline__ void unit_mfma(f32x4 acc[8], const ushort_t* wf,
                                          const ushort_t* Ahi, const ushort_t* Alo,
                                          ushort_t* Bhi, ushort_t* Blo,
                                          int tid, int lane, int wid) {
  #pragma unroll 1
  for (int half = 0; half < 2; half++) {
    __syncthreads();
    const short8* ghi = (const short8*)(wf + half * 8192);
    const short8* glo = (const short8*)(wf + 16384 + half * 8192);
    #pragma unroll
    for (int i = 0; i < 4; i++) {
      ((short8*)Bhi)[tid + i * 256] = ghi[tid + i * 256];
      ((short8*)Blo)[tid + i * 256] = glo[tid + i * 256];
    }
    __syncthreads();
    #pragma unroll
    for (int ks2 = 0; ks2 < 2; ks2++) {
      int ksA = half * 2 + ks2;
      short8 ah = *(const short8*)&Ahi[((wid * 4 + ksA) * 64 + lane) * 8];
      short8 al = *(const short8*)&Alo[((wid * 4 + ksA) * 64 + lane) * 8];
      #pragma unroll
      for (int ct = 0; ct < 8; ct++) {
        short8 bh = *(const short8*)&Bhi[((ks2 * 8 + ct) * 64 + lane) * 8];
        short8 bl = *(const short8*)&Blo[((ks2 * 8 + ct) * 64 + lane) * 8];
        acc[ct] = __builtin_amdgcn_mfma_f32_16x16x32_bf16(ah, bh, acc[ct], 0, 0, 0);
        acc[ct] = __builtin_amdgcn_mfma_f32_16x16x32_bf16(ah, bl, acc[ct], 0, 0, 0);
        acc[ct] = __builtin_amdgcn_mfma_f32_16x16x32_bf16(al, bh, acc[ct], 0, 0, 0);
      }
    }
  }
}

// ---- N-half unit (4 col-tiles, ct0 = 0 or 4): half the B-stage + MFMA ----
__device__ __forceinline__ void unit_mfma_h(f32x4 acc[4], const ushort_t* wf,
                                            int ct0,
                                            const ushort_t* Ahi, const ushort_t* Alo,
                                            ushort_t* Bhi, ushort_t* Blo,
                                            int tid, int lane, int wid) {
  #pragma unroll 1
  for (int half = 0; half < 2; half++) {
    __syncthreads();
    #pragma unroll
    for (int i = 0; i < 2; i++) {
      int sc = tid + i * 256;             // 0..511
      int ks2 = sc >> 8;
      int cts = (sc >> 6) & 3;
      int ln  = sc & 63;
      int c = half * 1024 + ks2 * 512 + (ct0 + cts) * 64 + ln;
      ((short8*)Bhi)[sc] = *(const short8*)&wf[(size_t)c * 8];
      ((short8*)Blo)[sc] = *(const short8*)&wf[16384 + (size_t)c * 8];
    }
    __syncthreads();
    #pragma unroll
    for (int ks2 = 0; ks2 < 2; ks2++) {
      int ksA = half * 2 + ks2;
      short8 ah = *(const short8*)&Ahi[((wid * 4 + ksA) * 64 + lane) * 8];
      short8 al = *(const short8*)&Alo[((wid * 4 + ksA) * 64 + lane) * 8];
      #pragma unroll
      for (int ct = 0; ct < 4; ct++) {
        short8 bh = *(const short8*)&Bhi[((ks2 * 4 + ct) * 64 + lane) * 8];
        short8 bl = *(const short8*)&Blo[((ks2 * 4 + ct) * 64 + lane) * 8];
        acc[ct] = __builtin_amdgcn_mfma_f32_16x16x32_bf16(ah, bh, acc[ct], 0, 0, 0);
        acc[ct] = __builtin_amdgcn_mfma_f32_16x16x32_bf16(ah, bl, acc[ct], 0, 0, 0);
        acc[ct] = __builtin_amdgcn_mfma_f32_16x16x32_bf16(al, bh, acc[ct], 0, 0, 0);
      }
    }
  }
}

// ---------------- g1 (N-split): out = [relu](A@W + bias), grid (256,2) -----
template<int RELU>
__global__ __launch_bounds__(256, 4) void g1_kernel(
    const float* __restrict__ A, const ushort_t* __restrict__ wf,
    const float* __restrict__ bias, float* __restrict__ out) {
  __shared__ ushort_t Ahi[8192], Alo[8192], Bhi[4096], Blo[4096];
  const int tid = threadIdx.x, lane = tid & 63, wid = tid >> 6;
  const int m0 = blockIdx.x * 64, ct0 = blockIdx.y * 4;
  stage_A_convert(Ahi, Alo, A, m0, tid);
  f32x4 acc[4];
  f32x4 z = {0.f, 0.f, 0.f, 0.f};
  #pragma unroll
  for (int ct = 0; ct < 4; ct++) acc[ct] = z;
  unit_mfma_h(acc, wf, ct0, Ahi, Alo, Bhi, Blo, tid, lane, wid);

  const int rbase = m0 + wid * 16 + ((lane >> 4) << 2);
  const int cb = lane & 15;
  #pragma unroll
  for (int ct = 0; ct < 4; ct++) {
    int n = (ct0 + ct) * 16 + cb;
    float bv = bias ? bias[n] : 0.f;
    #pragma unroll
    for (int r = 0; r < 4; r++) {
      float v = acc[ct][r] + bv;
      if (RELU) v = fmaxf(v, 0.f);
      out[(size_t)(rbase + r) * HID + n] = v;
    }
  }
}

// ---------------- msg pair (full-N, grid (256,2) y=top/bot) — r9 form ------
__global__ __launch_bounds__(256, 4) void msg_kernel(
    const float* __restrict__ h, const ushort_t* __restrict__ wfT,
    const ushort_t* __restrict__ wfB, const float* __restrict__ mb,
    float* __restrict__ bufA, float* __restrict__ bufB) {
  __shared__ ushort_t Ahi[8192], Alo[8192], Bhi[8192], Blo[8192];
  const int tid = threadIdx.x, lane = tid & 63, wid = tid >> 6;
  const int m0 = blockIdx.x * 64;
  const int y = blockIdx.y;
  stage_A_convert(Ahi, Alo, h, m0, tid);
  f32x4 acc[8];
  f32x4 z = {0.f, 0.f, 0.f, 0.f};
  #pragma unroll
  for (int ct = 0; ct < 8; ct++) acc[ct] = z;
  unit_mfma(acc, y ? wfB : wfT, Ahi, Alo, Bhi, Blo, tid, lane, wid);

  float* out = y ? bufB : bufA;
  const float* bias = y ? mb : nullptr;
  const int rbase = m0 + wid * 16 + ((lane >> 4) << 2);
  const int cb = lane & 15;
  #pragma unroll
  for (int ct = 0; ct < 8; ct++) {
    int n = ct * 16 + cb;
    float bv = bias ? bias[n] : 0.f;
    #pragma unroll
    for (int r = 0; r < 4; r++)
      out[(size_t)(rbase + r) * HID + n] = acc[ct][r] + bv;
  }
}

// ---------------- upd (N-split): h' = h + relu(h@Wt + agg@Wb + ub) ---------
__global__ __launch_bounds__(256, 4) void upd_kernel(
    const float* __restrict__ h, const ushort_t* __restrict__ wuT,
    const float* __restrict__ aggF, const ushort_t* __restrict__ wuB,
    const float* __restrict__ ub, float* __restrict__ out) {
  __shared__ ushort_t Ahi[8192], Alo[8192], Bhi[4096], Blo[4096];
  const int tid = threadIdx.x, lane = tid & 63, wid = tid >> 6;
  const int m0 = blockIdx.x * 64, ct0 = blockIdx.y * 4;
  stage_A_convert(Ahi, Alo, h, m0, tid);
  f32x4 acc[4];
  f32x4 z = {0.f, 0.f, 0.f, 0.f};
  #pragma unroll
  for (int ct = 0; ct < 4; ct++) acc[ct] = z;
  unit_mfma_h(acc, wuT, ct0, Ahi, Alo, Bhi, Blo, tid, lane, wid);
  __syncthreads();                         // phase-1 A reads done
  stage_A_convert(Ahi, Alo, aggF, m0, tid);
  unit_mfma_h(acc, wuB, ct0, Ahi, Alo, Bhi, Blo, tid, lane, wid);

  const int rbase = m0 + wid * 16 + ((lane >> 4) << 2);
  const int cb = lane & 15;
  #pragma unroll
  for (int ct = 0; ct < 4; ct++) {
    int n = (ct0 + ct) * 16 + cb;
    float bv = ub[n];
    #pragma unroll
    for (int r = 0; r < 4; r++) {
      float v = fmaxf(acc[ct][r] + bv, 0.f)
              + h[(size_t)(rbase + r) * HID + n];
      out[(size_t)(rbase + r) * HID + n] = v;
    }
  }
}

// ---------------- proj1 (full-N, grid (256,2) y=col-block) — r9 form -------
__global__ __launch_bounds__(256, 4) void proj1_kernel(
    const float* __restrict__ A, const ushort_t* __restrict__ wf01,
    const float* __restrict__ pb1, float* __restrict__ zout) {
  __shared__ ushort_t Ahi[8192], Alo[8192], Bhi[8192], Blo[8192];
  const int tid = threadIdx.x, lane = tid & 63, wid = tid >> 6;
  const int m0 = blockIdx.x * 64;
  const int y = blockIdx.y;
  stage_A_convert(Ahi, Alo, A, m0, tid);
  f32x4 acc[8];
  f32x4 z = {0.f, 0.f, 0.f, 0.f};
  #pragma unroll
  for (int ct = 0; ct < 8; ct++) acc[ct] = z;
  unit_mfma(acc, wf01 + (size_t)y * 32768, Ahi, Alo, Bhi, Blo, tid, lane, wid);

  const int rbase = m0 + wid * 16 + ((lane >> 4) << 2);
  const int cb = lane & 15;
  #pragma unroll
  for (int ct = 0; ct < 8; ct++) {
    int n = y * 128 + ct * 16 + cb;
    float bv = pb1[n];
    #pragma unroll
    for (int r = 0; r < 4; r++)
      zout[(size_t)(rbase + r) * PROJ_D + n] = acc[ct][r] + bv;
  }
}

// ---------------- fused message + mean-aggregation (2 nodes/block) --------
__global__ __launch_bounds__(256) void agg_kernel(const float* __restrict__ Abuf,
                                                  const float* __restrict__ Bbuf,
                                                  const int* __restrict__ row_ptr,
                                                  const int* __restrict__ col,
                                                  float* __restrict__ agg) {
  int j = blockIdx.x * 2 + (threadIdx.x >> 7);
  int c = threadIdx.x & 127;
  float bj = Bbuf[(size_t)j * HID + c];
  int s = row_ptr[j], e = row_ptr[j + 1];
  float acc = 0.f;
  int p = s;
  for (; p + 4 <= e; p += 4) {
    int i0 = col[p], i1 = col[p+1], i2 = col[p+2], i3 = col[p+3];
    float v0 = Abuf[(size_t)i0 * HID + c];
    float v1 = Abuf[(size_t)i1 * HID + c];
    float v2 = Abuf[(size_t)i2 * HID + c];
    float v3 = Abuf[(size_t)i3 * HID + c];
    acc += fmaxf(v0 + bj, 0.f) + fmaxf(v1 + bj, 0.f)
         + fmaxf(v2 + bj, 0.f) + fmaxf(v3 + bj, 0.f);
  }
  for (; p < e; p++) {
    int i = col[p];
    acc += fmaxf(Abuf[(size_t)i * HID + c] + bj, 0.f);
  }
  float deg = (float)(e - s);
  float inv = 1.0f / fmaxf(deg, 1.0f);
  agg[(size_t)j * HID + c] = acc * inv;
}

extern "C" void kernel_launch(void* const* d_in, const int* in_sizes, int n_in,
                              void* d_out, int out_size, void* d_ws, size_t ws_size,
                              hipStream_t stream) {
  (void)in_sizes; (void)n_in; (void)out_size; (void)ws_size;
  const float* x       = (const float*)d_in[0];
  const float* pos     = (const float*)d_in[1];
  const float* enc_w0  = (const float*)d_in[3];
  const float* enc_b0  = (const float*)d_in[4];
  const float* enc_w1  = (const float*)d_in[5];
  const float* enc_b1  = (const float*)d_in[6];
  const float* msg_w   = (const float*)d_in[7];
  const float* msg_b   = (const float*)d_in[8];
  const float* upd_w   = (const float*)d_in[9];
  const float* upd_b   = (const float*)d_in[10];
  const float* proj_w0 = (const float*)d_in[11];
  const float* proj_b0 = (const float*)d_in[12];
  const float* proj_w1 = (const float*)d_in[13];
  const float* proj_b1 = (const float*)d_in[14];

  char* ws = (char*)d_ws;
  size_t off = 0;
  auto alloc = [&](size_t bytes) -> void* {
    void* p = ws + off;
    off += (bytes + 255) & ~(size_t)255;
    return p;
  };
  int*      nbr     = (int*)alloc((size_t)EE * 4);
  int*      cnt     = (int*)alloc((size_t)BN * 4);
  int*      fill    = (int*)alloc((size_t)BN * 4);
  int*      row_ptr = (int*)alloc((size_t)(BN + 1) * 4);
  int*      col     = (int*)alloc((size_t)EE * 4);
  float*    h_a     = (float*)alloc((size_t)BN * HID * 4);
  float*    h_b     = (float*)alloc((size_t)BN * HID * 4);
  float*    bufA    = (float*)alloc((size_t)BN * HID * 4);
  float*    bufB    = (float*)alloc((size_t)BN * HID * 4);
  float*    bufAgg  = (float*)alloc((size_t)BN * HID * 4);
  ushort_t* wfrag   = (ushort_t*)alloc((size_t)16 * 32768 * 2);
  float*    out     = (float*)d_out;
  float*    hOut    = out + (size_t)BN * PROJ_D;

  hipMemsetAsync(cnt, 0, (size_t)BN * 4 * 2, stream);   // cnt + fill

  prep_w_kernel<<<128, 256, 0, stream>>>(enc_w1, msg_w, upd_w, proj_w0, proj_w1, wfrag);
  knn_kernel<<<BN / QPB, 1024, 0, stream>>>(pos, nbr, cnt);
  scan_kernel<<<1, 256, 0, stream>>>(cnt, row_ptr);
  fill_kernel<<<EE / 256, 256, 0, stream>>>(nbr, row_ptr, fill, col);

  enc0_kernel<<<BN * 32 / 256, 256, 0, stream>>>(x, enc_w0, enc_b0, bufA);
  g1_kernel<1><<<dim3(BN / 64, 2), 256, 0, stream>>>(bufA, wfrag + 0 * 32768,
                                                     enc_b1, h_a);

  float* hc = h_a;
  float* hn = h_b;
  for (int i = 0; i < 3; i++) {
    msg_kernel<<<dim3(BN / 64, 2), 256, 0, stream>>>(
        hc, wfrag + (size_t)(1 + 2 * i) * 32768,
        wfrag + (size_t)(2 + 2 * i) * 32768, msg_b + (size_t)i * HID,
        bufA, bufB);
    agg_kernel<<<BN / 2, 256, 0, stream>>>(bufA, bufB, row_ptr, col, bufAgg);
    float* target = (i == 2) ? hOut : hn;
    upd_kernel<<<dim3(BN / 64, 2), 256, 0, stream>>>(
        hc, wfrag + (size_t)(7 + 2 * i) * 32768, bufAgg,
        wfrag + (size_t)(8 + 2 * i) * 32768, upd_b + (size_t)i * HID, target);
    hn = hc; hc = target;
  }

  g1_kernel<1><<<dim3(BN / 64, 2), 256, 0, stream>>>(hc, wfrag + 13 * 32768,
                                                     proj_b0, bufA);
  proj1_kernel<<<dim3(BN / 64, 2), 256, 0, stream>>>(
      bufA, wfrag + 14 * 32768, proj_b1, out);
}